// Round 3
// baseline (752.842 us; speedup 1.0000x reference)
//
#include <hip/hip_runtime.h>
#include <stdint.h>

// Problem: out[t,b,c,h,w] = (t - 64*x >= 0) * (uniform(fold_in(key(0),1)) <= 0.75)
// out shape (64,16,3,224,224) fp32; N = 154,140,672 < 2^32.
static constexpr uint32_t T = 64;
static constexpr uint32_t M = 16u * 3u * 224u * 224u;  // 2,408,448 per timestep

// uniform = bitcast((bits>>9)|0x3F800000)-1 <= 0.75  <=>  bits <= 0xC00001FF
static constexpr uint32_t BITS_LE = 0xC00001FFu;

#define ROTL(x, n) (((x) << (n)) | ((x) >> (32 - (n))))

// Threefry-2x32, 20 rounds. JAX partitionable random_bits (default since
// 0.4.36) for bit_width=32 returns bits1 ^ bits2 (XOR of BOTH output words),
// with counts = (hi32(j), lo32(j)) = (0, j) here since N < 2^32.
__device__ __forceinline__ uint32_t tf2x32_xor(uint32_t k0, uint32_t k1,
                                               uint32_t x0, uint32_t x1) {
  const uint32_t ks2 = k0 ^ k1 ^ 0x1BD11BDAu;
  x0 += k0; x1 += k1;
#define R4(ra, rb, rc, rd) \
  x0 += x1; x1 = ROTL(x1, ra); x1 ^= x0; \
  x0 += x1; x1 = ROTL(x1, rb); x1 ^= x0; \
  x0 += x1; x1 = ROTL(x1, rc); x1 ^= x0; \
  x0 += x1; x1 = ROTL(x1, rd); x1 ^= x0;
  R4(13, 15, 26, 6)   x0 += k1;  x1 += ks2 + 1u;
  R4(17, 29, 16, 24)  x0 += ks2; x1 += k0 + 2u;
  R4(13, 15, 26, 6)   x0 += k0;  x1 += k1 + 3u;
  R4(17, 29, 16, 24)  x0 += k1;  x1 += ks2 + 4u;
  R4(13, 15, 26, 6)   x0 += ks2; x1 += k0 + 5u;
#undef R4
  return x0 ^ x1;
}

// grid = (M/4/256, 64) = (2352, 64); blockIdx.y = timestep t.
// Each thread: 4 consecutive spatial elements -> 4 independent threefry
// chains (ILP) + one float4 store.
__global__ __launch_bounds__(256) void spike_encode(const float* __restrict__ x,
                                                    float* __restrict__ out,
                                                    uint32_t rk0, uint32_t rk1) {
  const uint32_t m4 = (blockIdx.x * 256u + threadIdx.x) * 4u;
  const uint32_t t  = blockIdx.y;
  const float tf = (float)t;

  const float4 xv = *reinterpret_cast<const float4*>(x + m4);

  const uint32_t j = t * M + m4;  // flat index, fits u32
  const uint32_t b0 = tf2x32_xor(rk0, rk1, 0u, j + 0u);
  const uint32_t b1 = tf2x32_xor(rk0, rk1, 0u, j + 1u);
  const uint32_t b2 = tf2x32_xor(rk0, rk1, 0u, j + 2u);
  const uint32_t b3 = tf2x32_xor(rk0, rk1, 0u, j + 3u);

  float4 o;
  // (t - x*64 >= 0) exactly as fp32; *64 is an exact pow2 scale.
  o.x = (((tf - xv.x * 64.0f) >= 0.0f) && (b0 <= BITS_LE)) ? 1.0f : 0.0f;
  o.y = (((tf - xv.y * 64.0f) >= 0.0f) && (b1 <= BITS_LE)) ? 1.0f : 0.0f;
  o.z = (((tf - xv.z * 64.0f) >= 0.0f) && (b2 <= BITS_LE)) ? 1.0f : 0.0f;
  o.w = (((tf - xv.w * 64.0f) >= 0.0f) && (b3 <= BITS_LE)) ? 1.0f : 0.0f;

  *reinterpret_cast<float4*>(out + (size_t)j) = o;
}

// Host-side full threefry2x32 (both words) for the fold_in key derivation.
static inline void tf2x32_host(uint32_t k0, uint32_t k1, uint32_t& x0, uint32_t& x1) {
  const uint32_t ks2 = k0 ^ k1 ^ 0x1BD11BDAu;
  x0 += k0; x1 += k1;
  auto rnd = [&](int r) { x0 += x1; x1 = (x1 << r) | (x1 >> (32 - r)); x1 ^= x0; };
  rnd(13); rnd(15); rnd(26); rnd(6);  x0 += k1;  x1 += ks2 + 1u;
  rnd(17); rnd(29); rnd(16); rnd(24); x0 += ks2; x1 += k0 + 2u;
  rnd(13); rnd(15); rnd(26); rnd(6);  x0 += k0;  x1 += k1 + 3u;
  rnd(17); rnd(29); rnd(16); rnd(24); x0 += k1;  x1 += ks2 + 4u;
  rnd(13); rnd(15); rnd(26); rnd(6);  x0 += ks2; x1 += k0 + 5u;
}

extern "C" void kernel_launch(void* const* d_in, const int* in_sizes, int n_in,
                              void* d_out, int out_size, void* d_ws, size_t ws_size,
                              hipStream_t stream) {
  (void)in_sizes; (void)n_in; (void)out_size; (void)d_ws; (void)ws_size;
  const float* x = (const float*)d_in[0];
  float* out = (float*)d_out;

  // rkey = fold_in(key(0), 1) = threefry2x32(key=(0,0), counts=(0,1))
  uint32_t rk0 = 0u, rk1 = 1u;
  tf2x32_host(0u, 0u, rk0, rk1);

  dim3 grid(M / 4u / 256u, T);  // (2352, 64)
  spike_encode<<<grid, dim3(256), 0, stream>>>(x, out, rk0, rk1);
}